// Round 1
// baseline (2191.899 us; speedup 1.0000x reference)
//
#include <hip/hip_runtime.h>

#define USER_NUM 120000
#define ITEM_NUM 80000
#define N_NODES (USER_NUM + ITEM_NUM)
#define N_EDGES 3200000
#define EMBED_DIM 64

// ---------------------------------------------------------------------------
// init: buf0 = concat(user, item); pooled = same; buf1 = 0
// ---------------------------------------------------------------------------
__global__ void init_kernel(const float* __restrict__ user,
                            const float* __restrict__ item,
                            float* __restrict__ embeds,
                            float* __restrict__ pooled,
                            float* __restrict__ zbuf) {
    const int total4 = N_NODES * EMBED_DIM / 4;
    const int user4  = USER_NUM * EMBED_DIM / 4;
    int idx = blockIdx.x * blockDim.x + threadIdx.x;
    const int stride = gridDim.x * blockDim.x;
    const float4* u4 = (const float4*)user;
    const float4* i4 = (const float4*)item;
    float4* e4 = (float4*)embeds;
    float4* p4 = (float4*)pooled;
    float4* z4 = (float4*)zbuf;
    const float4 zero = make_float4(0.f, 0.f, 0.f, 0.f);
    for (; idx < total4; idx += stride) {
        float4 v = (idx < user4) ? u4[idx] : i4[idx - user4];
        e4[idx] = v;
        p4[idx] = v;
        z4[idx] = zero;
    }
}

// ---------------------------------------------------------------------------
// spmm: one wave (64 lanes) per edge; lane d handles dim d.
// out[r*64+d] += v * in[c*64+d]   (out must be pre-zeroed)
// ---------------------------------------------------------------------------
__global__ void spmm_kernel(const int* __restrict__ rows,
                            const int* __restrict__ cols,
                            const float* __restrict__ vals,
                            const float* __restrict__ in,
                            float* __restrict__ out) {
    const int lane = threadIdx.x & 63;
    int wid = (blockIdx.x * blockDim.x + threadIdx.x) >> 6;
    const int nw = (gridDim.x * blockDim.x) >> 6;
    for (int e = wid; e < N_EDGES; e += nw) {
        const int r = rows[e];
        const int c = cols[e];
        const float v = vals[e];
        const float x = in[((size_t)c << 6) + lane];
#if defined(__HIP_PLATFORM_AMD__)
        unsafeAtomicAdd(&out[((size_t)r << 6) + lane], v * x);
#else
        atomicAdd(&out[((size_t)r << 6) + lane], v * x);
#endif
    }
}

// ---------------------------------------------------------------------------
// pooled += src; optionally zero zbuf (the buffer the NEXT spmm writes into)
// ---------------------------------------------------------------------------
__global__ void add_zero_kernel(float* __restrict__ pooled,
                                const float* __restrict__ src,
                                float* __restrict__ zbuf,
                                int do_zero) {
    const int total4 = N_NODES * EMBED_DIM / 4;
    int idx = blockIdx.x * blockDim.x + threadIdx.x;
    const int stride = gridDim.x * blockDim.x;
    float4* p4 = (float4*)pooled;
    const float4* s4 = (const float4*)src;
    float4* z4 = (float4*)zbuf;
    const float4 zero = make_float4(0.f, 0.f, 0.f, 0.f);
    for (; idx < total4; idx += stride) {
        float4 p = p4[idx];
        float4 s = s4[idx];
        p.x += s.x; p.y += s.y; p.z += s.z; p.w += s.w;
        p4[idx] = p;
        if (do_zero) z4[idx] = zero;
    }
}

extern "C" void kernel_launch(void* const* d_in, const int* in_sizes, int n_in,
                              void* d_out, int out_size, void* d_ws, size_t ws_size,
                              hipStream_t stream) {
    const float* user = (const float*)d_in[0];
    const float* item = (const float*)d_in[1];
    const int*   rows = (const int*)d_in[2];
    const int*   cols = (const int*)d_in[3];
    const float* vals = (const float*)d_in[4];

    float* pooled = (float*)d_out;                         // [N_NODES, 64]
    float* buf0 = (float*)d_ws;                            // [N_NODES, 64]
    float* buf1 = buf0 + (size_t)N_NODES * EMBED_DIM;      // [N_NODES, 64]

    const dim3 blk(256);
    const dim3 grid_ew(2048);     // elementwise: grid-stride
    const dim3 grid_spmm(8192);   // 4 waves/block -> 32768 waves over 3.2M edges

    init_kernel<<<grid_ew, blk, 0, stream>>>(user, item, buf0, pooled, buf1);

    // layer 1: buf0 -> buf1
    spmm_kernel<<<grid_spmm, blk, 0, stream>>>(rows, cols, vals, buf0, buf1);
    add_zero_kernel<<<grid_ew, blk, 0, stream>>>(pooled, buf1, buf0, 1);

    // layer 2: buf1 -> buf0
    spmm_kernel<<<grid_spmm, blk, 0, stream>>>(rows, cols, vals, buf1, buf0);
    add_zero_kernel<<<grid_ew, blk, 0, stream>>>(pooled, buf0, buf1, 1);

    // layer 3: buf0 -> buf1
    spmm_kernel<<<grid_spmm, blk, 0, stream>>>(rows, cols, vals, buf0, buf1);
    add_zero_kernel<<<grid_ew, blk, 0, stream>>>(pooled, buf1, buf0, 0);
}

// Round 2
// 1137.157 us; speedup vs baseline: 1.9275x; 1.9275x over previous
//
#include <hip/hip_runtime.h>

#define USER_NUM 120000
#define ITEM_NUM 80000
#define N_NODES (USER_NUM + ITEM_NUM)
#define N_EDGES 3200000
#define EMBED_DIM 64
#define SCAN_BLOCKS ((N_NODES + 255) / 256)   // 782

// ---------------------------------------------------------------------------
// init: buf0 = concat(user, item); pooled = same
// ---------------------------------------------------------------------------
__global__ void init_kernel(const float* __restrict__ user,
                            const float* __restrict__ item,
                            float* __restrict__ embeds,
                            float* __restrict__ pooled) {
    const int total4 = N_NODES * EMBED_DIM / 4;
    const int user4  = USER_NUM * EMBED_DIM / 4;
    int idx = blockIdx.x * blockDim.x + threadIdx.x;
    const int stride = gridDim.x * blockDim.x;
    const float4* u4 = (const float4*)user;
    const float4* i4 = (const float4*)item;
    float4* e4 = (float4*)embeds;
    float4* p4 = (float4*)pooled;
    for (; idx < total4; idx += stride) {
        float4 v = (idx < user4) ? u4[idx] : i4[idx - user4];
        e4[idx] = v;
        p4[idx] = v;
    }
}

// ---------------------------------------------------------------------------
// counting-sort by row: histogram -> scan -> scatter
// ---------------------------------------------------------------------------
__global__ void hist_kernel(const int* __restrict__ rows, int* __restrict__ counts) {
    int e = blockIdx.x * blockDim.x + threadIdx.x;
    if (e < N_EDGES) atomicAdd(&counts[rows[e]], 1);
}

// per-block exclusive scan of counts -> row_start (partial), block totals out
__global__ void scan_blocks_kernel(const int* __restrict__ counts,
                                   int* __restrict__ row_start,
                                   int* __restrict__ block_sums) {
    const int i = blockIdx.x * 256 + threadIdx.x;
    const int lane = threadIdx.x & 63;
    const int wid = threadIdx.x >> 6;
    int x = (i < N_NODES) ? counts[i] : 0;
    int v = x;
    #pragma unroll
    for (int d = 1; d < 64; d <<= 1) {
        int y = __shfl_up(v, d);
        if (lane >= d) v += y;
    }
    __shared__ int wsum[4];
    if (lane == 63) wsum[wid] = v;
    __syncthreads();
    if (threadIdx.x == 0) {
        int s = 0;
        #pragma unroll
        for (int w = 0; w < 4; ++w) { int t = wsum[w]; wsum[w] = s; s += t; }
        block_sums[blockIdx.x] = s;
    }
    __syncthreads();
    const int excl = wsum[wid] + v - x;
    if (i < N_NODES) row_start[i] = excl;
}

// single-wave exclusive scan of block totals (in place)
__global__ void scan_totals_kernel(int* __restrict__ block_sums) {
    const int lane = threadIdx.x;  // blockDim = 64
    int carry = 0;
    for (int base = 0; base < SCAN_BLOCKS; base += 64) {
        const int i = base + lane;
        int x = (i < SCAN_BLOCKS) ? block_sums[i] : 0;
        int v = x;
        #pragma unroll
        for (int d = 1; d < 64; d <<= 1) {
            int y = __shfl_up(v, d);
            if (lane >= d) v += y;
        }
        if (i < SCAN_BLOCKS) block_sums[i] = carry + v - x;
        carry += __shfl(v, 63);
    }
}

// add block offsets; duplicate into cursor for the scatter pass
__global__ void scan_add_kernel(int* __restrict__ row_start,
                                int* __restrict__ cursor,
                                const int* __restrict__ block_sums) {
    const int i = blockIdx.x * 256 + threadIdx.x;
    if (i < N_NODES) {
        const int v = row_start[i] + block_sums[blockIdx.x];
        row_start[i] = v;
        cursor[i] = v;
    }
}

// scatter edges into row-sorted order, packing (col, val) as int2
__global__ void scatter_kernel(const int* __restrict__ rows,
                               const int* __restrict__ cols,
                               const float* __restrict__ vals,
                               int* __restrict__ cursor,
                               int2* __restrict__ cv) {
    int e = blockIdx.x * blockDim.x + threadIdx.x;
    if (e < N_EDGES) {
        const int r = rows[e];
        const int pos = atomicAdd(&cursor[r], 1);
        cv[pos] = make_int2(cols[e], __float_as_int(vals[e]));
    }
}

// ---------------------------------------------------------------------------
// CSR SpMM: one wave per row; lanes cooperatively stage 64 (col,val) pairs,
// shfl-broadcast each edge, accumulate in register; fused pooled += acc.
// ---------------------------------------------------------------------------
__global__ void spmm_csr_kernel(const int* __restrict__ row_start,
                                const int* __restrict__ counts,
                                const int2* __restrict__ cv,
                                const float* __restrict__ in,
                                float* __restrict__ out,
                                float* __restrict__ pooled) {
    const int lane = threadIdx.x & 63;
    const int row = (blockIdx.x * blockDim.x + threadIdx.x) >> 6;
    if (row >= N_NODES) return;
    const int start = row_start[row];
    const int end = start + counts[row];
    float acc = 0.f;
    for (int base = start; base < end; base += 64) {
        const int rem = end - base;
        int c_l = 0; float v_l = 0.f;
        if (lane < rem) {
            const int2 p = cv[base + lane];
            c_l = p.x; v_l = __int_as_float(p.y);
        }
        const int m = rem < 64 ? rem : 64;
        for (int k = 0; k < m; ++k) {
            const int c = __shfl(c_l, k);
            const float v = __shfl(v_l, k);
            acc = fmaf(v, in[((size_t)c << 6) + lane], acc);
        }
    }
    const size_t o = ((size_t)row << 6) + lane;
    out[o] = acc;
    pooled[o] += acc;
}

extern "C" void kernel_launch(void* const* d_in, const int* in_sizes, int n_in,
                              void* d_out, int out_size, void* d_ws, size_t ws_size,
                              hipStream_t stream) {
    const float* user = (const float*)d_in[0];
    const float* item = (const float*)d_in[1];
    const int*   rows = (const int*)d_in[2];
    const int*   cols = (const int*)d_in[3];
    const float* vals = (const float*)d_in[4];

    float* pooled = (float*)d_out;                           // [N, 64]

    // workspace layout
    char* p = (char*)d_ws;
    float* buf0      = (float*)p;  p += (size_t)N_NODES * EMBED_DIM * 4;   // 51.2 MB
    float* buf1      = (float*)p;  p += (size_t)N_NODES * EMBED_DIM * 4;   // 51.2 MB
    int2*  cv        = (int2*)p;   p += (size_t)N_EDGES * 8;               // 25.6 MB
    int*   counts    = (int*)p;    p += (size_t)N_NODES * 4;
    int*   row_start = (int*)p;    p += (size_t)N_NODES * 4;
    int*   cursor    = (int*)p;    p += (size_t)N_NODES * 4;
    int*   bsums     = (int*)p;    p += (size_t)SCAN_BLOCKS * 4;

    const dim3 blk(256);
    const dim3 grid_ew(2048);
    const dim3 grid_edge((N_EDGES + 255) / 256);        // 12500
    const dim3 grid_scan(SCAN_BLOCKS);                  // 782
    const dim3 grid_spmm((N_NODES * 64 + 255) / 256);   // 50000 (4 waves/blk)

    hipMemsetAsync(counts, 0, (size_t)N_NODES * 4, stream);
    init_kernel<<<grid_ew, blk, 0, stream>>>(user, item, buf0, pooled);

    // build CSR (counting sort by row)
    hist_kernel<<<grid_edge, blk, 0, stream>>>(rows, counts);
    scan_blocks_kernel<<<grid_scan, blk, 0, stream>>>(counts, row_start, bsums);
    scan_totals_kernel<<<1, 64, 0, stream>>>(bsums);
    scan_add_kernel<<<grid_scan, blk, 0, stream>>>(row_start, cursor, bsums);
    scatter_kernel<<<grid_edge, blk, 0, stream>>>(rows, cols, vals, cursor, cv);

    // 3 gather-based SpMMs with fused pooled accumulation
    spmm_csr_kernel<<<grid_spmm, blk, 0, stream>>>(row_start, counts, cv, buf0, buf1, pooled);
    spmm_csr_kernel<<<grid_spmm, blk, 0, stream>>>(row_start, counts, cv, buf1, buf0, pooled);
    spmm_csr_kernel<<<grid_spmm, blk, 0, stream>>>(row_start, counts, cv, buf0, buf1, pooled);
}

// Round 3
// 939.456 us; speedup vs baseline: 2.3332x; 1.2104x over previous
//
#include <hip/hip_runtime.h>

#define USER_NUM 120000
#define ITEM_NUM 80000
#define N_NODES (USER_NUM + ITEM_NUM)
#define N_EDGES 3200000
#define EMBED_DIM 64
#define SCAN_BLOCKS ((N_NODES + 255) / 256)   // 782

// ---------------------------------------------------------------------------
// init: buf0 = concat(user, item); pooled = same
// ---------------------------------------------------------------------------
__global__ void init_kernel(const float* __restrict__ user,
                            const float* __restrict__ item,
                            float* __restrict__ embeds,
                            float* __restrict__ pooled) {
    const int total4 = N_NODES * EMBED_DIM / 4;
    const int user4  = USER_NUM * EMBED_DIM / 4;
    int idx = blockIdx.x * blockDim.x + threadIdx.x;
    const int stride = gridDim.x * blockDim.x;
    const float4* u4 = (const float4*)user;
    const float4* i4 = (const float4*)item;
    float4* e4 = (float4*)embeds;
    float4* p4 = (float4*)pooled;
    for (; idx < total4; idx += stride) {
        float4 v = (idx < user4) ? u4[idx] : i4[idx - user4];
        e4[idx] = v;
        p4[idx] = v;
    }
}

// ---------------------------------------------------------------------------
// counting-sort by row: histogram -> scan -> scatter
// ---------------------------------------------------------------------------
__global__ void hist_kernel(const int* __restrict__ rows, int* __restrict__ counts) {
    int e = blockIdx.x * blockDim.x + threadIdx.x;
    if (e < N_EDGES) atomicAdd(&counts[rows[e]], 1);
}

__global__ void scan_blocks_kernel(const int* __restrict__ counts,
                                   int* __restrict__ row_start,
                                   int* __restrict__ block_sums) {
    const int i = blockIdx.x * 256 + threadIdx.x;
    const int lane = threadIdx.x & 63;
    const int wid = threadIdx.x >> 6;
    int x = (i < N_NODES) ? counts[i] : 0;
    int v = x;
    #pragma unroll
    for (int d = 1; d < 64; d <<= 1) {
        int y = __shfl_up(v, d);
        if (lane >= d) v += y;
    }
    __shared__ int wsum[4];
    if (lane == 63) wsum[wid] = v;
    __syncthreads();
    if (threadIdx.x == 0) {
        int s = 0;
        #pragma unroll
        for (int w = 0; w < 4; ++w) { int t = wsum[w]; wsum[w] = s; s += t; }
        block_sums[blockIdx.x] = s;
    }
    __syncthreads();
    const int excl = wsum[wid] + v - x;
    if (i < N_NODES) row_start[i] = excl;
}

__global__ void scan_totals_kernel(int* __restrict__ block_sums) {
    const int lane = threadIdx.x;  // blockDim = 64
    int carry = 0;
    for (int base = 0; base < SCAN_BLOCKS; base += 64) {
        const int i = base + lane;
        int x = (i < SCAN_BLOCKS) ? block_sums[i] : 0;
        int v = x;
        #pragma unroll
        for (int d = 1; d < 64; d <<= 1) {
            int y = __shfl_up(v, d);
            if (lane >= d) v += y;
        }
        if (i < SCAN_BLOCKS) block_sums[i] = carry + v - x;
        carry += __shfl(v, 63);
    }
}

__global__ void scan_add_kernel(int* __restrict__ row_start,
                                int* __restrict__ cursor,
                                const int* __restrict__ block_sums) {
    const int i = blockIdx.x * 256 + threadIdx.x;
    if (i < N_NODES) {
        const int v = row_start[i] + block_sums[blockIdx.x];
        row_start[i] = v;
        cursor[i] = v;
    }
}

__global__ void scatter_kernel(const int* __restrict__ rows,
                               const int* __restrict__ cols,
                               const float* __restrict__ vals,
                               int* __restrict__ cursor,
                               int2* __restrict__ cv) {
    int e = blockIdx.x * blockDim.x + threadIdx.x;
    if (e < N_EDGES) {
        const int r = rows[e];
        const int pos = atomicAdd(&cursor[r], 1);
        cv[pos] = make_int2(cols[e], __float_as_int(vals[e]));
    }
}

// ---------------------------------------------------------------------------
// CSR SpMM: one wave per row, 4 groups x 16 lanes. Group g handles edge
// base+g; lane-in-group gl holds dims [4*gl, 4*gl+4). (col,val) are uniform
// within a group (no shfl); gather is one dwordx4 covering 4 edges/wave.
// Cross-group partials combined with shfl_xor(16/32). Fused pooled += acc.
// ---------------------------------------------------------------------------
__global__ void spmm_csr_kernel(const int* __restrict__ row_start,
                                const int* __restrict__ counts,
                                const int2* __restrict__ cv,
                                const float* __restrict__ in,
                                float* __restrict__ out,
                                float* __restrict__ pooled,
                                int write_out) {
    const int lane = threadIdx.x & 63;
    const int row = (blockIdx.x * blockDim.x + threadIdx.x) >> 6;
    if (row >= N_NODES) return;
    const int g  = lane >> 4;    // edge group 0..3
    const int gl = lane & 15;    // dim-slice lane
    const int start = row_start[row];
    const int end = start + counts[row];
    float ax = 0.f, ay = 0.f, az = 0.f, aw = 0.f;
    for (int base = start; base < end; base += 4) {
        const int e = base + g;
        if (e < end) {
            const int2 p = cv[e];
            const float v = __int_as_float(p.y);
            const float4 x = *(const float4*)&in[((size_t)p.x << 6) + (gl << 2)];
            ax = fmaf(v, x.x, ax);
            ay = fmaf(v, x.y, ay);
            az = fmaf(v, x.z, az);
            aw = fmaf(v, x.w, aw);
        }
    }
    // combine the 4 groups' partials (lanes gl, gl+16, gl+32, gl+48)
    ax += __shfl_xor(ax, 16); ay += __shfl_xor(ay, 16);
    az += __shfl_xor(az, 16); aw += __shfl_xor(aw, 16);
    ax += __shfl_xor(ax, 32); ay += __shfl_xor(ay, 32);
    az += __shfl_xor(az, 32); aw += __shfl_xor(aw, 32);
    if (lane < 16) {
        const size_t o = ((size_t)row << 6) + (gl << 2);
        const float4 acc = make_float4(ax, ay, az, aw);
        if (write_out) *(float4*)&out[o] = acc;
        float4 pv = *(const float4*)&pooled[o];
        pv.x += acc.x; pv.y += acc.y; pv.z += acc.z; pv.w += acc.w;
        *(float4*)&pooled[o] = pv;
    }
}

extern "C" void kernel_launch(void* const* d_in, const int* in_sizes, int n_in,
                              void* d_out, int out_size, void* d_ws, size_t ws_size,
                              hipStream_t stream) {
    const float* user = (const float*)d_in[0];
    const float* item = (const float*)d_in[1];
    const int*   rows = (const int*)d_in[2];
    const int*   cols = (const int*)d_in[3];
    const float* vals = (const float*)d_in[4];

    float* pooled = (float*)d_out;                           // [N, 64]

    // workspace layout
    char* p = (char*)d_ws;
    float* buf0      = (float*)p;  p += (size_t)N_NODES * EMBED_DIM * 4;   // 51.2 MB
    float* buf1      = (float*)p;  p += (size_t)N_NODES * EMBED_DIM * 4;   // 51.2 MB
    int2*  cv        = (int2*)p;   p += (size_t)N_EDGES * 8;               // 25.6 MB
    int*   counts    = (int*)p;    p += (size_t)N_NODES * 4;
    int*   row_start = (int*)p;    p += (size_t)N_NODES * 4;
    int*   cursor    = (int*)p;    p += (size_t)N_NODES * 4;
    int*   bsums     = (int*)p;    p += (size_t)SCAN_BLOCKS * 4;

    const dim3 blk(256);
    const dim3 grid_ew(2048);
    const dim3 grid_edge((N_EDGES + 255) / 256);        // 12500
    const dim3 grid_scan(SCAN_BLOCKS);                  // 782
    const dim3 grid_spmm((N_NODES + 3) / 4);            // 4 rows (waves) per block

    hipMemsetAsync(counts, 0, (size_t)N_NODES * 4, stream);
    init_kernel<<<grid_ew, blk, 0, stream>>>(user, item, buf0, pooled);

    // build CSR (counting sort by row)
    hist_kernel<<<grid_edge, blk, 0, stream>>>(rows, counts);
    scan_blocks_kernel<<<grid_scan, blk, 0, stream>>>(counts, row_start, bsums);
    scan_totals_kernel<<<1, 64, 0, stream>>>(bsums);
    scan_add_kernel<<<grid_scan, blk, 0, stream>>>(row_start, cursor, bsums);
    scatter_kernel<<<grid_edge, blk, 0, stream>>>(rows, cols, vals, cursor, cv);

    // 3 gather-based SpMMs with fused pooled accumulation
    spmm_csr_kernel<<<grid_spmm, blk, 0, stream>>>(row_start, counts, cv, buf0, buf1, pooled, 1);
    spmm_csr_kernel<<<grid_spmm, blk, 0, stream>>>(row_start, counts, cv, buf1, buf0, pooled, 1);
    spmm_csr_kernel<<<grid_spmm, blk, 0, stream>>>(row_start, counts, cv, buf0, buf1, pooled, 0);
}

// Round 5
// 899.722 us; speedup vs baseline: 2.4362x; 1.0442x over previous
//
#include <hip/hip_runtime.h>

#define USER_NUM 120000
#define ITEM_NUM 80000
#define N_NODES (USER_NUM + ITEM_NUM)
#define N_EDGES 3200000
#define EMBED_DIM 64
#define SCAN_BLOCKS ((N_NODES + 255) / 256)   // 782

// ---------------------------------------------------------------------------
// init: buf0 = concat(user, item); pooled = same
// ---------------------------------------------------------------------------
__global__ void init_kernel(const float* __restrict__ user,
                            const float* __restrict__ item,
                            float* __restrict__ embeds,
                            float* __restrict__ pooled) {
    const int total4 = N_NODES * EMBED_DIM / 4;
    const int user4  = USER_NUM * EMBED_DIM / 4;
    int idx = blockIdx.x * blockDim.x + threadIdx.x;
    const int stride = gridDim.x * blockDim.x;
    const float4* u4 = (const float4*)user;
    const float4* i4 = (const float4*)item;
    float4* e4 = (float4*)embeds;
    float4* p4 = (float4*)pooled;
    for (; idx < total4; idx += stride) {
        float4 v = (idx < user4) ? u4[idx] : i4[idx - user4];
        e4[idx] = v;
        p4[idx] = v;
    }
}

// ---------------------------------------------------------------------------
// counting-sort by row: histogram -> scan -> scatter
// ---------------------------------------------------------------------------
__global__ void hist_kernel(const int* __restrict__ rows, int* __restrict__ counts) {
    int e = blockIdx.x * blockDim.x + threadIdx.x;
    if (e < N_EDGES) atomicAdd(&counts[rows[e]], 1);
}

__global__ void scan_blocks_kernel(const int* __restrict__ counts,
                                   int* __restrict__ row_start,
                                   int* __restrict__ block_sums) {
    const int i = blockIdx.x * 256 + threadIdx.x;
    const int lane = threadIdx.x & 63;
    const int wid = threadIdx.x >> 6;
    int x = (i < N_NODES) ? counts[i] : 0;
    int v = x;
    #pragma unroll
    for (int d = 1; d < 64; d <<= 1) {
        int y = __shfl_up(v, d);
        if (lane >= d) v += y;
    }
    __shared__ int wsum[4];
    if (lane == 63) wsum[wid] = v;
    __syncthreads();
    if (threadIdx.x == 0) {
        int s = 0;
        #pragma unroll
        for (int w = 0; w < 4; ++w) { int t = wsum[w]; wsum[w] = s; s += t; }
        block_sums[blockIdx.x] = s;
    }
    __syncthreads();
    const int excl = wsum[wid] + v - x;
    if (i < N_NODES) row_start[i] = excl;
}

__global__ void scan_totals_kernel(int* __restrict__ block_sums) {
    const int lane = threadIdx.x;  // blockDim = 64
    int carry = 0;
    for (int base = 0; base < SCAN_BLOCKS; base += 64) {
        const int i = base + lane;
        int x = (i < SCAN_BLOCKS) ? block_sums[i] : 0;
        int v = x;
        #pragma unroll
        for (int d = 1; d < 64; d <<= 1) {
            int y = __shfl_up(v, d);
            if (lane >= d) v += y;
        }
        if (i < SCAN_BLOCKS) block_sums[i] = carry + v - x;
        carry += __shfl(v, 63);
    }
}

__global__ void scan_add_kernel(int* __restrict__ row_start,
                                int* __restrict__ cursor,
                                const int* __restrict__ block_sums) {
    const int i = blockIdx.x * 256 + threadIdx.x;
    if (i < N_NODES) {
        const int v = row_start[i] + block_sums[blockIdx.x];
        row_start[i] = v;
        cursor[i] = v;
    }
}

__global__ void scatter_kernel(const int* __restrict__ rows,
                               const int* __restrict__ cols,
                               const float* __restrict__ vals,
                               int* __restrict__ cursor,
                               int2* __restrict__ cv) {
    int e = blockIdx.x * blockDim.x + threadIdx.x;
    if (e < N_EDGES) {
        const int r = rows[e];
        const int pos = atomicAdd(&cursor[r], 1);
        cv[pos] = make_int2(cols[e], __float_as_int(vals[e]));
    }
}

// ---------------------------------------------------------------------------
// CSR SpMM: one wave per row, 4 groups x 16 lanes. The row's (col,val) list
// is staged with ONE coalesced 64-lane load, then broadcast per-edge via
// __shfl. Inner loop bounds are WAVE-UNIFORM (k4 steps of 4, uniform rem);
// invalid lanes clamp the shfl index and use v=0, so every __shfl executes
// with all 64 lanes active (shfl from exited lanes is UB -- R4 bug).
// Group g handles edge k4+g; lane-in-group gl holds dims [4*gl, 4*gl+4).
// Cross-group partials combined with shfl_xor(16/32). Fused pooled += acc.
// ---------------------------------------------------------------------------
__global__ void spmm_csr_kernel(const int* __restrict__ row_start,
                                const int* __restrict__ counts,
                                const int2* __restrict__ cv,
                                const float* __restrict__ in,
                                float* __restrict__ out,
                                float* __restrict__ pooled,
                                int write_out) {
    const int lane = threadIdx.x & 63;
    const int row = (blockIdx.x * blockDim.x + threadIdx.x) >> 6;
    if (row >= N_NODES) return;
    const int g  = lane >> 4;    // edge group 0..3
    const int gl = lane & 15;    // dim-slice lane
    const int start = row_start[row];
    const int deg = counts[row];
    float ax = 0.f, ay = 0.f, az = 0.f, aw = 0.f;
    for (int chunk = 0; chunk < deg; chunk += 64) {
        const int rem = min(64, deg - chunk);
        // stage up to 64 (col,val) pairs: one coalesced wave load
        const int2 p = cv[start + chunk + min(lane, rem - 1)];
        #pragma unroll 4
        for (int k4 = 0; k4 < rem; k4 += 4) {   // uniform bounds: no lane exits
            const int k = k4 + g;
            const bool valid = k < rem;
            const int kc = valid ? k : rem - 1;
            const int   c = __shfl(p.x, kc);
            float v = __int_as_float(__shfl(p.y, kc));
            if (!valid) v = 0.f;
            const float4 x = *(const float4*)&in[((size_t)c << 6) + (gl << 2)];
            ax = fmaf(v, x.x, ax);
            ay = fmaf(v, x.y, ay);
            az = fmaf(v, x.z, az);
            aw = fmaf(v, x.w, aw);
        }
    }
    // combine the 4 groups' partials (lanes gl, gl+16, gl+32, gl+48)
    ax += __shfl_xor(ax, 16); ay += __shfl_xor(ay, 16);
    az += __shfl_xor(az, 16); aw += __shfl_xor(aw, 16);
    ax += __shfl_xor(ax, 32); ay += __shfl_xor(ay, 32);
    az += __shfl_xor(az, 32); aw += __shfl_xor(aw, 32);
    if (lane < 16) {
        const size_t o = ((size_t)row << 6) + (gl << 2);
        const float4 acc = make_float4(ax, ay, az, aw);
        if (write_out) *(float4*)&out[o] = acc;
        float4 pv = *(const float4*)&pooled[o];
        pv.x += acc.x; pv.y += acc.y; pv.z += acc.z; pv.w += acc.w;
        *(float4*)&pooled[o] = pv;
    }
}

extern "C" void kernel_launch(void* const* d_in, const int* in_sizes, int n_in,
                              void* d_out, int out_size, void* d_ws, size_t ws_size,
                              hipStream_t stream) {
    const float* user = (const float*)d_in[0];
    const float* item = (const float*)d_in[1];
    const int*   rows = (const int*)d_in[2];
    const int*   cols = (const int*)d_in[3];
    const float* vals = (const float*)d_in[4];

    float* pooled = (float*)d_out;                           // [N, 64]

    // workspace layout
    char* p = (char*)d_ws;
    float* buf0      = (float*)p;  p += (size_t)N_NODES * EMBED_DIM * 4;   // 51.2 MB
    float* buf1      = (float*)p;  p += (size_t)N_NODES * EMBED_DIM * 4;   // 51.2 MB
    int2*  cv        = (int2*)p;   p += (size_t)N_EDGES * 8;               // 25.6 MB
    int*   counts    = (int*)p;    p += (size_t)N_NODES * 4;
    int*   row_start = (int*)p;    p += (size_t)N_NODES * 4;
    int*   cursor    = (int*)p;    p += (size_t)N_NODES * 4;
    int*   bsums     = (int*)p;    p += (size_t)SCAN_BLOCKS * 4;

    const dim3 blk(256);
    const dim3 grid_ew(2048);
    const dim3 grid_edge((N_EDGES + 255) / 256);        // 12500
    const dim3 grid_scan(SCAN_BLOCKS);                  // 782
    const dim3 grid_spmm((N_NODES + 3) / 4);            // 4 rows (waves) per block

    hipMemsetAsync(counts, 0, (size_t)N_NODES * 4, stream);
    init_kernel<<<grid_ew, blk, 0, stream>>>(user, item, buf0, pooled);

    // build CSR (counting sort by row)
    hist_kernel<<<grid_edge, blk, 0, stream>>>(rows, counts);
    scan_blocks_kernel<<<grid_scan, blk, 0, stream>>>(counts, row_start, bsums);
    scan_totals_kernel<<<1, 64, 0, stream>>>(bsums);
    scan_add_kernel<<<grid_scan, blk, 0, stream>>>(row_start, cursor, bsums);
    scatter_kernel<<<grid_edge, blk, 0, stream>>>(rows, cols, vals, cursor, cv);

    // 3 gather-based SpMMs with fused pooled accumulation
    spmm_csr_kernel<<<grid_spmm, blk, 0, stream>>>(row_start, counts, cv, buf0, buf1, pooled, 1);
    spmm_csr_kernel<<<grid_spmm, blk, 0, stream>>>(row_start, counts, cv, buf1, buf0, pooled, 1);
    spmm_csr_kernel<<<grid_spmm, blk, 0, stream>>>(row_start, counts, cv, buf0, buf1, pooled, 0);
}